// Round 7
// baseline (6253.297 us; speedup 1.0000x reference)
//
#include <hip/hip_runtime.h>
#include <hip/hip_bf16.h>

#define N_NODES 50000
#define DEG     16
#define IN_CH   128
#define TYPE_DIM 32
#define F_DIM   160      // = IN_CH + TYPE_DIM
#define H_DIM   160
#define OUT_CH  128
#define NSTEP   16       // = DEG timesteps
#define LS      168      // LDS row stride in ushorts (16B-aligned)

typedef short  bf16x8 __attribute__((ext_vector_type(8)));
typedef float  f32x4  __attribute__((ext_vector_type(4)));
typedef unsigned int u32x4 __attribute__((ext_vector_type(4)));

// Workspace in __device__ globals (cached VRAM) — R5 proved d_ws is mapped
// uncached/streaming. Fully rewritten every call.
__device__ ushort g_hin[N_NODES * F_DIM];       // 16,000,000 B
__device__ ushort g_wfrag[400 * 64 * 8];        // 409,600 B
__device__ ushort g_wlrfrag[80 * 64 * 8];       // 81,920 B
__device__ float  g_bsum[4 * H_DIM];            // 2,560 B

static __device__ __forceinline__ ushort f2bf(float v) {
    union { float f; unsigned u; } x; x.f = v;
    unsigned r = x.u + 0x7fff + ((x.u >> 16) & 1);   // RNE
    return (ushort)(r >> 16);
}
static __device__ __forceinline__ float sigmoid_fast(float x) {
    return 1.f / (1.f + __expf(-x));
}
static __device__ __forceinline__ float tanh_fast(float x) {
    float e = __expf(2.f * x);
    return 1.f - 2.f / (e + 1.f);
}

// ---------------------------------------------------------------------------
// Pack weights into MFMA B-fragment order (bf16), and sum biases.
// Main W frags: frag = qg*40 + kc*4 + p   (qg 0..9, kc 0..9 K-chunk, p gate i/f/g/o)
//   frag[lane] = 8 bf16 of W[row = p*160 + qg*16 + (lane&15)][k = kcL*32 + (lane>>4)*8 + j]
//   kc<5 -> W_ih (X part), kc>=5 -> W_hh (H part)
// Final W frags: frag = kc*8 + nt : row = nt*16+(lane&15), k<160 -> W_l, else W_r
// ---------------------------------------------------------------------------
__global__ void pack_kernel(const float* __restrict__ Wih, const float* __restrict__ Whh,
                            const float* __restrict__ bih, const float* __restrict__ bhh,
                            const float* __restrict__ Wl,  const float* __restrict__ Wr)
{
    int gid = blockIdx.x * 256 + threadIdx.x;
    if (gid < 400 * 64) {
        int frag = gid >> 6, lane = gid & 63;
        int p = frag & 3, kc = (frag >> 2) % 10, qg = frag / 40;
        int row = p * 160 + qg * 16 + (lane & 15);
        int quad = lane >> 4;
        const float* src; int k0;
        if (kc < 5) { src = Wih + row * 160; k0 = kc * 32 + quad * 8; }
        else        { src = Whh + row * 160; k0 = (kc - 5) * 32 + quad * 8; }
        ushort tmp[8];
        #pragma unroll
        for (int j = 0; j < 8; j++) tmp[j] = f2bf(src[k0 + j]);
        ((u32x4*)g_wfrag)[frag * 64 + lane] = *(const u32x4*)tmp;
    } else if (gid < 400 * 64 + 80 * 64) {
        int g2 = gid - 400 * 64;
        int frag = g2 >> 6, lane = g2 & 63;
        int nt = frag & 7, kc = frag >> 3;
        int row = nt * 16 + (lane & 15);
        int quad = lane >> 4;
        int k0 = kc * 32 + quad * 8;
        ushort tmp[8];
        #pragma unroll
        for (int j = 0; j < 8; j++) {
            int k = k0 + j;
            float v = (k < 160) ? Wl[row * 160 + k] : Wr[row * 160 + (k - 160)];
            tmp[j] = f2bf(v);
        }
        ((u32x4*)g_wlrfrag)[frag * 64 + lane] = *(const u32x4*)tmp;
    } else if (gid < 400 * 64 + 80 * 64 + 640) {
        int i = gid - (400 * 64 + 80 * 64);
        g_bsum[i] = bih[i] + bhh[i];
    }
}

// h_in = concat(x, emb[type]) as bf16 rows of 160 (320 B, 16B aligned)
__global__ void build_hin(const float* __restrict__ x, const int* __restrict__ tids,
                          const float* __restrict__ emb)
{
    int i = blockIdx.x * 256 + threadIdx.x;
    if (i >= N_NODES * F_DIM) return;
    int n = i / F_DIM, d = i - n * F_DIM;
    float v = (d < IN_CH) ? x[n * IN_CH + d] : emb[tids[n] * TYPE_DIM + (d - IN_CH)];
    g_hin[i] = f2bf(v);
}

// ---------------------------------------------------------------------------
// Fused LSTM-aggregation + SAGE linear.
// Block = 64 nodes, 640 threads = 10 waves. Wave wv owns qg group wv:
// 16 gate-cols x 4 gates x ALL 64 nodes (4 A-frags) -> each weight fragment
// is loaded ONCE per block per step (no duplication; 4x MFMA reuse per frag).
// Single Hb buffer (43KB LDS -> 3 blocks/CU = 30 waves). h_new parks in regs,
// committed next write phase. Next neighbor row prefetched into regs during
// compute. Bias folded into acc init. Per-wave state ~110 VGPR (no spills).
// ---------------------------------------------------------------------------
__launch_bounds__(640, 8)
__global__ void lstm_sage(const int* __restrict__ edge_src,
                          const float* __restrict__ bl,
                          float* __restrict__ out)
{
    __shared__ ushort Xb[64 * LS];
    __shared__ ushort Hb[64 * LS];

    const int tid  = threadIdx.x;
    const int lane = tid & 63;
    const int wv   = tid >> 6;           // 0..9 = qg group
    const int col  = lane & 15, quad = lane >> 4;
    const int nb   = blockIdx.x * 64;

    // per-lane gate biases for this wave's qg (dim = wv*16 + col)
    float bG4[4];
    #pragma unroll
    for (int p = 0; p < 4; p++) bG4[p] = g_bsum[p * 160 + wv * 16 + col];

    for (int i = tid; i < 64 * LS; i += 640) Hb[i] = 0;   // h0 = 0

    float c_st[4][4];
    #pragma unroll
    for (int m = 0; m < 4; m++)
        #pragma unroll
        for (int r = 0; r < 4; r++) c_st[m][r] = 0.f;

    unsigned hn[4][2];   // packed bf16 h_new (row pairs), parked in regs

    const int grow  = tid / 10;          // 64 rows x 10 threads
    const int gpart = tid - grow * 10;   // 0..9, segs gpart and gpart+10
    const int node_g = nb + grow;
    const int sbase = (node_g < N_NODES ? node_g : 0) * DEG;

    // prime: X_0 row segs + index for t=1
    u32x4 P0, P1;
    {
        int s = edge_src[sbase];
        const u32x4* sp = (const u32x4*)(g_hin + s * F_DIM);
        P0 = sp[gpart]; P1 = sp[gpart + 10];
    }
    int snext = edge_src[sbase + 1];

    #pragma unroll 1
    for (int t = 0; t < NSTEP; t++) {
        // ---- write phase: commit h(t-1) and X_t (both already in registers)
        if (t > 0) {
            #pragma unroll
            for (int m = 0; m < 4; m++)
                #pragma unroll
                for (int k = 0; k < 2; k++) {
                    int a = (m * 16 + quad * 4 + 2 * k) * LS + wv * 16 + col;
                    unsigned pk = hn[m][k];
                    Hb[a]      = (ushort)pk;
                    Hb[a + LS] = (ushort)(pk >> 16);
                }
        }
        {
            u32x4* dp = (u32x4*)(Xb + grow * LS);
            dp[gpart] = P0; dp[gpart + 10] = P1;
        }
        __syncthreads();   // Xb + Hb valid for step t

        // ---- prefetch for t+1 (t=15 slot: own row, for the lin_r stage)
        {
            const u32x4* sp = (t < NSTEP - 1)
                ? (const u32x4*)(g_hin + snext * F_DIM)
                : (const u32x4*)(g_hin + (node_g < N_NODES ? node_g : 0) * F_DIM);
            P0 = sp[gpart]; P1 = sp[gpart + 10];
            snext = edge_src[sbase + ((t + 2 < DEG) ? t + 2 : 0)];
        }

        // ---- compute phase: gates for all 64 nodes, this wave's qg
        f32x4 acc[4][4];
        #pragma unroll
        for (int m = 0; m < 4; m++)
            #pragma unroll
            for (int p = 0; p < 4; p++)
                acc[m][p] = (f32x4){bG4[p], bG4[p], bG4[p], bG4[p]};

        const u32x4* wq = (const u32x4*)g_wfrag + wv * 40 * 64 + lane;
        #pragma unroll
        for (int kc = 0; kc < 10; kc++) {
            bf16x8 bfr[4];
            #pragma unroll
            for (int p = 0; p < 4; p++) {
                u32x4 u = wq[(kc * 4 + p) * 64];
                bfr[p] = *(const bf16x8*)&u;
            }
            const ushort* ab = ((kc < 5) ? (Xb + kc * 32) : (Hb + (kc - 5) * 32))
                               + col * LS + quad * 8;
            bf16x8 afr[4];
            #pragma unroll
            for (int m = 0; m < 4; m++)
                afr[m] = *(const bf16x8*)(ab + m * (16 * LS));
            #pragma unroll
            for (int m = 0; m < 4; m++)
                #pragma unroll
                for (int p = 0; p < 4; p++)
                    acc[m][p] = __builtin_amdgcn_mfma_f32_16x16x32_bf16(
                        afr[m], bfr[p], acc[m][p], 0, 0, 0);
        }
        // LSTM elementwise (D-layout: node row = quad*4 + r) -> park in hn
        #pragma unroll
        for (int m = 0; m < 4; m++) {
            #pragma unroll
            for (int k = 0; k < 2; k++) {
                unsigned pk = 0;
                #pragma unroll
                for (int h2 = 0; h2 < 2; h2++) {
                    int r = 2 * k + h2;
                    float c = sigmoid_fast(acc[m][1][r]) * c_st[m][r]
                            + sigmoid_fast(acc[m][0][r]) * tanh_fast(acc[m][2][r]);
                    c_st[m][r] = c;
                    float h = sigmoid_fast(acc[m][3][r]) * tanh_fast(c);
                    pk |= ((unsigned)f2bf(h)) << (16 * h2);
                }
                hn[m][k] = pk;
            }
        }
        __syncthreads();   // all reads of Xb/Hb done -> next write may overwrite
    }

    // ---- epilogue: commit h(15); stage own h_in row (already in P)
    #pragma unroll
    for (int m = 0; m < 4; m++)
        #pragma unroll
        for (int k = 0; k < 2; k++) {
            int a = (m * 16 + quad * 4 + 2 * k) * LS + wv * 16 + col;
            unsigned pk = hn[m][k];
            Hb[a]      = (ushort)pk;
            Hb[a + LS] = (ushort)(pk >> 16);
        }
    {
        u32x4* dp = (u32x4*)(Xb + grow * LS);
        dp[gpart] = P0; dp[gpart + 10] = P1;
    }
    __syncthreads();

    // out = relu([h_last | h_in] @ [W_l | W_r]^T + b_l)
    // waves 0..7: wave = (m = wv&3, phalf = wv>>2); waves 8,9 idle (no barriers)
    if (wv < 8) {
        const int m = wv & 3, pb = (wv >> 2) * 4;
        f32x4 acc[4];
        #pragma unroll
        for (int p = 0; p < 4; p++) {
            float b = bl[(pb + p) * 16 + col];
            acc[p] = (f32x4){b, b, b, b};
        }
        const u32x4* wq2 = (const u32x4*)g_wlrfrag + lane;
        #pragma unroll
        for (int kc = 0; kc < 10; kc++) {
            bf16x8 bfr[4];
            #pragma unroll
            for (int p = 0; p < 4; p++) {
                u32x4 u = wq2[(kc * 8 + pb + p) * 64];
                bfr[p] = *(const bf16x8*)&u;
            }
            const ushort* ab = ((kc < 5) ? (Hb + kc * 32) : (Xb + (kc - 5) * 32))
                               + (m * 16 + col) * LS + quad * 8;
            bf16x8 afr = *(const bf16x8*)ab;
            #pragma unroll
            for (int p = 0; p < 4; p++)
                acc[p] = __builtin_amdgcn_mfma_f32_16x16x32_bf16(afr, bfr[p], acc[p], 0, 0, 0);
        }
        #pragma unroll
        for (int p = 0; p < 4; p++) {
            int ocol = (pb + p) * 16 + col;
            #pragma unroll
            for (int r = 0; r < 4; r++) {
                int node = nb + m * 16 + quad * 4 + r;
                if (node < N_NODES) {
                    float v = acc[p][r];
                    out[node * OUT_CH + ocol] = v > 0.f ? v : 0.f;
                }
            }
        }
    }
}

extern "C" void kernel_launch(void* const* d_in, const int* in_sizes, int n_in,
                              void* d_out, int out_size, void* d_ws, size_t ws_size,
                              hipStream_t stream)
{
    const float* x      = (const float*)d_in[0];
    const int*   tids   = (const int*)  d_in[1];
    const int*   esrc   = (const int*)  d_in[2];   // edge_index[0] = src (dst sorted, DEG each)
    const float* emb    = (const float*)d_in[3];
    const float* Wih    = (const float*)d_in[4];
    const float* Whh    = (const float*)d_in[5];
    const float* bih    = (const float*)d_in[6];
    const float* bhh    = (const float*)d_in[7];
    const float* Wl     = (const float*)d_in[8];
    const float* blin   = (const float*)d_in[9];
    const float* Wr     = (const float*)d_in[10];
    float* out = (float*)d_out;

    hipLaunchKernelGGL(pack_kernel, dim3(123), dim3(256), 0, stream,
                       Wih, Whh, bih, bhh, Wl, Wr);
    hipLaunchKernelGGL(build_hin, dim3((N_NODES * F_DIM + 255) / 256), dim3(256), 0, stream,
                       x, tids, emb);
    hipLaunchKernelGGL(lstm_sage, dim3((N_NODES + 63) / 64), dim3(640), 0, stream,
                       esrc, blin, out);
}

// Round 8
// 1318.844 us; speedup vs baseline: 4.7415x; 4.7415x over previous
//
#include <hip/hip_runtime.h>
#include <hip/hip_bf16.h>

#define N_NODES 50000
#define DEG     16
#define IN_CH   128
#define TYPE_DIM 32
#define F_DIM   160      // = IN_CH + TYPE_DIM
#define H_DIM   160
#define OUT_CH  128
#define NSTEP   16       // = DEG timesteps
#define LS      168      // LDS row stride in ushorts (16B-aligned)

typedef short  bf16x8 __attribute__((ext_vector_type(8)));
typedef float  f32x4  __attribute__((ext_vector_type(4)));
typedef unsigned int u32x4 __attribute__((ext_vector_type(4)));

// Workspace in __device__ globals (cached VRAM) — R5 proved d_ws is mapped
// uncached/streaming. Fully rewritten every call.
__device__ ushort g_hin[N_NODES * F_DIM];       // 16,000,000 B
__device__ ushort g_wfrag[400 * 64 * 8];        // 409,600 B
__device__ ushort g_wlrfrag[80 * 64 * 8];       // 81,920 B
__device__ float  g_bsum[4 * H_DIM];            // 2,560 B

static __device__ __forceinline__ ushort f2bf(float v) {
    union { float f; unsigned u; } x; x.f = v;
    unsigned r = x.u + 0x7fff + ((x.u >> 16) & 1);   // RNE
    return (ushort)(r >> 16);
}
static __device__ __forceinline__ float sigmoid_fast(float x) {
    return 1.f / (1.f + __expf(-x));
}
static __device__ __forceinline__ float tanh_fast(float x) {
    float e = __expf(2.f * x);
    return 1.f - 2.f / (e + 1.f);
}

// ---------------------------------------------------------------------------
// Pack weights into MFMA B-fragment order (bf16), and sum biases.
// Main W frags: frag = qg*40 + kc*4 + p   (qg 0..9, kc 0..9 K-chunk, p gate i/f/g/o)
//   frag[lane] = 8 bf16 of W[row = p*160 + qg*16 + (lane&15)][k = kcL*32 + (lane>>4)*8 + j]
//   kc<5 -> W_ih (X part), kc>=5 -> W_hh (H part)
// Final W frags: frag = kc*8 + nt : row = nt*16+(lane&15), k<160 -> W_l, else W_r
// ---------------------------------------------------------------------------
__global__ void pack_kernel(const float* __restrict__ Wih, const float* __restrict__ Whh,
                            const float* __restrict__ bih, const float* __restrict__ bhh,
                            const float* __restrict__ Wl,  const float* __restrict__ Wr)
{
    int gid = blockIdx.x * 256 + threadIdx.x;
    if (gid < 400 * 64) {
        int frag = gid >> 6, lane = gid & 63;
        int p = frag & 3, kc = (frag >> 2) % 10, qg = frag / 40;
        int row = p * 160 + qg * 16 + (lane & 15);
        int quad = lane >> 4;
        const float* src; int k0;
        if (kc < 5) { src = Wih + row * 160; k0 = kc * 32 + quad * 8; }
        else        { src = Whh + row * 160; k0 = (kc - 5) * 32 + quad * 8; }
        ushort tmp[8];
        #pragma unroll
        for (int j = 0; j < 8; j++) tmp[j] = f2bf(src[k0 + j]);
        ((u32x4*)g_wfrag)[frag * 64 + lane] = *(const u32x4*)tmp;
    } else if (gid < 400 * 64 + 80 * 64) {
        int g2 = gid - 400 * 64;
        int frag = g2 >> 6, lane = g2 & 63;
        int nt = frag & 7, kc = frag >> 3;
        int row = nt * 16 + (lane & 15);
        int quad = lane >> 4;
        int k0 = kc * 32 + quad * 8;
        ushort tmp[8];
        #pragma unroll
        for (int j = 0; j < 8; j++) {
            int k = k0 + j;
            float v = (k < 160) ? Wl[row * 160 + k] : Wr[row * 160 + (k - 160)];
            tmp[j] = f2bf(v);
        }
        ((u32x4*)g_wlrfrag)[frag * 64 + lane] = *(const u32x4*)tmp;
    } else if (gid < 400 * 64 + 80 * 64 + 640) {
        int i = gid - (400 * 64 + 80 * 64);
        g_bsum[i] = bih[i] + bhh[i];
    }
}

// h_in = concat(x, emb[type]) as bf16 rows of 160 (320 B, 16B aligned)
__global__ void build_hin(const float* __restrict__ x, const int* __restrict__ tids,
                          const float* __restrict__ emb)
{
    int i = blockIdx.x * 256 + threadIdx.x;
    if (i >= N_NODES * F_DIM) return;
    int n = i / F_DIM, d = i - n * F_DIM;
    float v = (d < IN_CH) ? x[n * IN_CH + d] : emb[tids[n] * TYPE_DIM + (d - IN_CH)];
    g_hin[i] = f2bf(v);
}

// ---------------------------------------------------------------------------
// Fused LSTM-aggregation + SAGE linear.
// Block = 64 nodes, 640 threads = 10 waves. Wave wv owns qg group wv:
// 16 gate-cols x 4 gates x ALL 64 nodes (4 A-frags) -> each weight fragment
// is loaded ONCE per block per step; 4x MFMA reuse per fragment.
// Single Hb buffer; h_new parks in regs, committed next write phase; next
// neighbor row prefetched into regs during compute.
//
// __launch_bounds__(640) — NO min-waves arg. gfx950 has a UNIFIED VGPR/AGPR
// file: the wave cap applies to vgpr+agpr combined. R6 (256,3)->170 cap and
// R7 (640,8)->64 cap both split the file (84+84 / 32+32) and spilled all
// scalar state to scratch (R7: 11.9GB scratch writes). Live state here is
// ~144 regs (64 acc + ~80 arch) which fits the launchability bound (~170
// for a 10-wave block: 3 waves on two SIMDs).
// ---------------------------------------------------------------------------
__launch_bounds__(640)
__global__ void lstm_sage(const int* __restrict__ edge_src,
                          const float* __restrict__ bl,
                          float* __restrict__ out)
{
    __shared__ ushort Xb[64 * LS];
    __shared__ ushort Hb[64 * LS];

    const int tid  = threadIdx.x;
    const int lane = tid & 63;
    const int wv   = tid >> 6;           // 0..9 = qg group
    const int col  = lane & 15, quad = lane >> 4;
    const int nb   = blockIdx.x * 64;

    // per-lane gate biases for this wave's qg (dim = wv*16 + col)
    float bG4[4];
    #pragma unroll
    for (int p = 0; p < 4; p++) bG4[p] = g_bsum[p * 160 + wv * 16 + col];

    for (int i = tid; i < 64 * LS; i += 640) Hb[i] = 0;   // h0 = 0

    float c_st[4][4];
    #pragma unroll
    for (int m = 0; m < 4; m++)
        #pragma unroll
        for (int r = 0; r < 4; r++) c_st[m][r] = 0.f;

    unsigned hn[4][2];   // packed bf16 h_new (row pairs), parked in regs

    const int grow  = tid / 10;          // 64 rows x 10 threads
    const int gpart = tid - grow * 10;   // 0..9, segs gpart and gpart+10
    const int node_g = nb + grow;
    const int sbase = (node_g < N_NODES ? node_g : 0) * DEG;

    // prime: X_0 row segs + index for t=1
    u32x4 P0, P1;
    {
        int s = edge_src[sbase];
        const u32x4* sp = (const u32x4*)(g_hin + s * F_DIM);
        P0 = sp[gpart]; P1 = sp[gpart + 10];
    }
    int snext = edge_src[sbase + 1];

    #pragma unroll 1
    for (int t = 0; t < NSTEP; t++) {
        // ---- write phase: commit h(t-1) and X_t (both already in registers)
        if (t > 0) {
            #pragma unroll
            for (int m = 0; m < 4; m++)
                #pragma unroll
                for (int k = 0; k < 2; k++) {
                    int a = (m * 16 + quad * 4 + 2 * k) * LS + wv * 16 + col;
                    unsigned pk = hn[m][k];
                    Hb[a]      = (ushort)pk;
                    Hb[a + LS] = (ushort)(pk >> 16);
                }
        }
        {
            u32x4* dp = (u32x4*)(Xb + grow * LS);
            dp[gpart] = P0; dp[gpart + 10] = P1;
        }
        __syncthreads();   // Xb + Hb valid for step t

        // ---- prefetch for t+1 (t=15 slot: own row, for the lin_r stage)
        {
            const u32x4* sp = (t < NSTEP - 1)
                ? (const u32x4*)(g_hin + snext * F_DIM)
                : (const u32x4*)(g_hin + (node_g < N_NODES ? node_g : 0) * F_DIM);
            P0 = sp[gpart]; P1 = sp[gpart + 10];
            snext = edge_src[sbase + ((t + 2 < DEG) ? t + 2 : 0)];
        }

        // ---- compute phase: gates for all 64 nodes, this wave's qg
        f32x4 acc[4][4];
        #pragma unroll
        for (int m = 0; m < 4; m++)
            #pragma unroll
            for (int p = 0; p < 4; p++)
                acc[m][p] = (f32x4){bG4[p], bG4[p], bG4[p], bG4[p]};

        const u32x4* wq = (const u32x4*)g_wfrag + wv * 40 * 64 + lane;
        #pragma unroll
        for (int kc = 0; kc < 10; kc++) {
            bf16x8 bfr[4];
            #pragma unroll
            for (int p = 0; p < 4; p++) {
                u32x4 u = wq[(kc * 4 + p) * 64];
                bfr[p] = *(const bf16x8*)&u;
            }
            const ushort* ab = ((kc < 5) ? (Xb + kc * 32) : (Hb + (kc - 5) * 32))
                               + col * LS + quad * 8;
            bf16x8 afr[4];
            #pragma unroll
            for (int m = 0; m < 4; m++)
                afr[m] = *(const bf16x8*)(ab + m * (16 * LS));
            #pragma unroll
            for (int m = 0; m < 4; m++)
                #pragma unroll
                for (int p = 0; p < 4; p++)
                    acc[m][p] = __builtin_amdgcn_mfma_f32_16x16x32_bf16(
                        afr[m], bfr[p], acc[m][p], 0, 0, 0);
        }
        // LSTM elementwise (D-layout: node row = quad*4 + r) -> park in hn
        #pragma unroll
        for (int m = 0; m < 4; m++) {
            #pragma unroll
            for (int k = 0; k < 2; k++) {
                unsigned pk = 0;
                #pragma unroll
                for (int h2 = 0; h2 < 2; h2++) {
                    int r = 2 * k + h2;
                    float c = sigmoid_fast(acc[m][1][r]) * c_st[m][r]
                            + sigmoid_fast(acc[m][0][r]) * tanh_fast(acc[m][2][r]);
                    c_st[m][r] = c;
                    float h = sigmoid_fast(acc[m][3][r]) * tanh_fast(c);
                    pk |= ((unsigned)f2bf(h)) << (16 * h2);
                }
                hn[m][k] = pk;
            }
        }
        __syncthreads();   // all reads of Xb/Hb done -> next write may overwrite
    }

    // ---- epilogue: commit h(15); stage own h_in row (already in P)
    #pragma unroll
    for (int m = 0; m < 4; m++)
        #pragma unroll
        for (int k = 0; k < 2; k++) {
            int a = (m * 16 + quad * 4 + 2 * k) * LS + wv * 16 + col;
            unsigned pk = hn[m][k];
            Hb[a]      = (ushort)pk;
            Hb[a + LS] = (ushort)(pk >> 16);
        }
    {
        u32x4* dp = (u32x4*)(Xb + grow * LS);
        dp[gpart] = P0; dp[gpart + 10] = P1;
    }
    __syncthreads();

    // out = relu([h_last | h_in] @ [W_l | W_r]^T + b_l)
    // waves 0..7: wave = (m = wv&3, phalf = wv>>2); waves 8,9 idle (no barriers)
    if (wv < 8) {
        const int m = wv & 3, pb = (wv >> 2) * 4;
        f32x4 acc[4];
        #pragma unroll
        for (int p = 0; p < 4; p++) {
            float b = bl[(pb + p) * 16 + col];
            acc[p] = (f32x4){b, b, b, b};
        }
        const u32x4* wq2 = (const u32x4*)g_wlrfrag + lane;
        #pragma unroll
        for (int kc = 0; kc < 10; kc++) {
            bf16x8 bfr[4];
            #pragma unroll
            for (int p = 0; p < 4; p++) {
                u32x4 u = wq2[(kc * 8 + pb + p) * 64];
                bfr[p] = *(const bf16x8*)&u;
            }
            const ushort* ab = ((kc < 5) ? (Hb + kc * 32) : (Xb + (kc - 5) * 32))
                               + (m * 16 + col) * LS + quad * 8;
            bf16x8 afr = *(const bf16x8*)ab;
            #pragma unroll
            for (int p = 0; p < 4; p++)
                acc[p] = __builtin_amdgcn_mfma_f32_16x16x32_bf16(afr, bfr[p], acc[p], 0, 0, 0);
        }
        #pragma unroll
        for (int p = 0; p < 4; p++) {
            int ocol = (pb + p) * 16 + col;
            #pragma unroll
            for (int r = 0; r < 4; r++) {
                int node = nb + m * 16 + quad * 4 + r;
                if (node < N_NODES) {
                    float v = acc[p][r];
                    out[node * OUT_CH + ocol] = v > 0.f ? v : 0.f;
                }
            }
        }
    }
}

extern "C" void kernel_launch(void* const* d_in, const int* in_sizes, int n_in,
                              void* d_out, int out_size, void* d_ws, size_t ws_size,
                              hipStream_t stream)
{
    const float* x      = (const float*)d_in[0];
    const int*   tids   = (const int*)  d_in[1];
    const int*   esrc   = (const int*)  d_in[2];   // edge_index[0] = src (dst sorted, DEG each)
    const float* emb    = (const float*)d_in[3];
    const float* Wih    = (const float*)d_in[4];
    const float* Whh    = (const float*)d_in[5];
    const float* bih    = (const float*)d_in[6];
    const float* bhh    = (const float*)d_in[7];
    const float* Wl     = (const float*)d_in[8];
    const float* blin   = (const float*)d_in[9];
    const float* Wr     = (const float*)d_in[10];
    float* out = (float*)d_out;

    hipLaunchKernelGGL(pack_kernel, dim3(123), dim3(256), 0, stream,
                       Wih, Whh, bih, bhh, Wl, Wr);
    hipLaunchKernelGGL(build_hin, dim3((N_NODES * F_DIM + 255) / 256), dim3(256), 0, stream,
                       x, tids, emb);
    hipLaunchKernelGGL(lstm_sage, dim3((N_NODES + 63) / 64), dim3(640), 0, stream,
                       esrc, blin, out);
}

// Round 10
// 1310.189 us; speedup vs baseline: 4.7728x; 1.0066x over previous
//
#include <hip/hip_runtime.h>
#include <hip/hip_bf16.h>

#define N_NODES 50000
#define DEG     16
#define IN_CH   128
#define TYPE_DIM 32
#define F_DIM   160      // = IN_CH + TYPE_DIM
#define H_DIM   160
#define OUT_CH  128
#define NSTEP   16       // = DEG timesteps
#define LS      168      // LDS row stride in ushorts (16B-aligned)

typedef short  bf16x8 __attribute__((ext_vector_type(8)));
typedef float  f32x4  __attribute__((ext_vector_type(4)));
typedef unsigned int u32x4 __attribute__((ext_vector_type(4)));

// Workspace in __device__ globals (cached VRAM) — R5 proved d_ws is mapped
// uncached/streaming. Fully rewritten every call.
__device__ ushort g_hin[N_NODES * F_DIM];       // 16,000,000 B
__device__ ushort g_wfrag[400 * 64 * 8];        // 409,600 B
__device__ ushort g_wlrfrag[80 * 64 * 8];       // 81,920 B
__device__ float  g_bsum[4 * H_DIM];            // 2,560 B

static __device__ __forceinline__ ushort f2bf(float v) {
    union { float f; unsigned u; } x; x.f = v;
    unsigned r = x.u + 0x7fff + ((x.u >> 16) & 1);   // RNE
    return (ushort)(r >> 16);
}
static __device__ __forceinline__ float sigmoid_fast(float x) {
    return 1.f / (1.f + __expf(-x));
}
static __device__ __forceinline__ float tanh_fast(float x) {
    float e = __expf(2.f * x);
    return 1.f - 2.f / (e + 1.f);
}

// ---------------------------------------------------------------------------
// Pack weights into MFMA B-fragment order (bf16), and sum biases.
// ---------------------------------------------------------------------------
__global__ void pack_kernel(const float* __restrict__ Wih, const float* __restrict__ Whh,
                            const float* __restrict__ bih, const float* __restrict__ bhh,
                            const float* __restrict__ Wl,  const float* __restrict__ Wr)
{
    int gid = blockIdx.x * 256 + threadIdx.x;
    if (gid < 400 * 64) {
        int frag = gid >> 6, lane = gid & 63;
        int p = frag & 3, kc = (frag >> 2) % 10, qg = frag / 40;
        int row = p * 160 + qg * 16 + (lane & 15);
        int quad = lane >> 4;
        const float* src; int k0;
        if (kc < 5) { src = Wih + row * 160; k0 = kc * 32 + quad * 8; }
        else        { src = Whh + row * 160; k0 = (kc - 5) * 32 + quad * 8; }
        ushort tmp[8];
        #pragma unroll
        for (int j = 0; j < 8; j++) tmp[j] = f2bf(src[k0 + j]);
        ((u32x4*)g_wfrag)[frag * 64 + lane] = *(const u32x4*)tmp;
    } else if (gid < 400 * 64 + 80 * 64) {
        int g2 = gid - 400 * 64;
        int frag = g2 >> 6, lane = g2 & 63;
        int nt = frag & 7, kc = frag >> 3;
        int row = nt * 16 + (lane & 15);
        int quad = lane >> 4;
        int k0 = kc * 32 + quad * 8;
        ushort tmp[8];
        #pragma unroll
        for (int j = 0; j < 8; j++) {
            int k = k0 + j;
            float v = (k < 160) ? Wl[row * 160 + k] : Wr[row * 160 + (k - 160)];
            tmp[j] = f2bf(v);
        }
        ((u32x4*)g_wlrfrag)[frag * 64 + lane] = *(const u32x4*)tmp;
    } else if (gid < 400 * 64 + 80 * 64 + 640) {
        int i = gid - (400 * 64 + 80 * 64);
        g_bsum[i] = bih[i] + bhh[i];
    }
}

// h_in = concat(x, emb[type]) as bf16 rows of 160 (320 B, 16B aligned)
__global__ void build_hin(const float* __restrict__ x, const int* __restrict__ tids,
                          const float* __restrict__ emb)
{
    int i = blockIdx.x * 256 + threadIdx.x;
    if (i >= N_NODES * F_DIM) return;
    int n = i / F_DIM, d = i - n * F_DIM;
    float v = (d < IN_CH) ? x[n * IN_CH + d] : emb[tids[n] * TYPE_DIM + (d - IN_CH)];
    g_hin[i] = f2bf(v);
}

// ---------------------------------------------------------------------------
// PRIMARY: fully double-buffered (Xb x2, Hb x2 = 84KB dynamic LDS),
// ONE barrier per step. Gather for t+1 streams straight into Xb[nxt] during
// step t; h(t) written straight into Hb[nxt] after the elementwise. No
// register parking. Block = 64 nodes, 640 threads = 10 waves, wave wv owns
// qg group wv (16 gate-cols x 4 gates x all 64 nodes). No min-waves arg —
// unified VGPR/AGPR file (R6/R7 lesson). Buffer select by integer offset
// (no LDS pointer arrays — addrspacecast static-init is unsupported).
// ---------------------------------------------------------------------------
__launch_bounds__(640)
__global__ void lstm_sage_db(const int* __restrict__ edge_src,
                             const float* __restrict__ bl,
                             float* __restrict__ out)
{
    extern __shared__ ushort lds[];
    constexpr int XOFF = 0;            // Xb[0], Xb[1] at XOFF + buf*64*LS
    constexpr int HOFF = 2 * 64 * LS;  // Hb[0], Hb[1] at HOFF + buf*64*LS
    constexpr int BSZ  = 64 * LS;

    const int tid  = threadIdx.x;
    const int lane = tid & 63;
    const int wv   = tid >> 6;           // 0..9 = qg group
    const int col  = lane & 15, quad = lane >> 4;
    const int nb   = blockIdx.x * 64;

    float bG4[4];
    #pragma unroll
    for (int p = 0; p < 4; p++) bG4[p] = g_bsum[p * 160 + wv * 16 + col];

    for (int i = tid; i < BSZ; i += 640) lds[HOFF + i] = 0;   // Hb[0] = h0 = 0

    float c_st[4][4];
    #pragma unroll
    for (int m = 0; m < 4; m++)
        #pragma unroll
        for (int r = 0; r < 4; r++) c_st[m][r] = 0.f;

    const int grow  = tid / 10;          // 64 rows x 10 threads
    const int gpart = tid - grow * 10;   // 0..9 -> segs gpart, gpart+10
    const int node_g = nb + grow;
    const int own = (node_g < N_NODES ? node_g : 0);
    const int sbase = own * DEG;

    // prime: X_0 -> Xb[0]
    {
        int s = edge_src[sbase];
        const u32x4* sp = (const u32x4*)(g_hin + s * F_DIM);
        u32x4* dp = (u32x4*)(lds + XOFF + grow * LS);
        dp[gpart]      = __builtin_nontemporal_load(sp + gpart);
        dp[gpart + 10] = __builtin_nontemporal_load(sp + gpart + 10);
    }
    int snext = edge_src[sbase + 1];

    // per-wave invariant addresses
    const int aoff = col * LS + quad * 8;           // A-frag offset within buffer
    const int hoff = quad * 4 * LS + wv * 16 + col; // h-commit base (row quad*4)

    #pragma unroll 1
    for (int t = 0; t < NSTEP; t++) {
        __syncthreads();   // Xb[cur]=X_t and Hb[cur]=h(t-1) visible
        const int cur = (t & 1) * BSZ, nxt = ((t & 1) ^ 1) * BSZ;

        // ---- gather X_{t+1} straight into Xb[nxt] (t=15 slot: own row)
        {
            const u32x4* sp = (const u32x4*)(g_hin + ((t < NSTEP - 1) ? snext : own) * F_DIM);
            u32x4 v0 = __builtin_nontemporal_load(sp + gpart);
            u32x4 v1 = __builtin_nontemporal_load(sp + gpart + 10);
            u32x4* dp = (u32x4*)(lds + XOFF + nxt + grow * LS);
            dp[gpart] = v0; dp[gpart + 10] = v1;
            snext = edge_src[sbase + ((t + 2 < DEG) ? t + 2 : 0)];
        }

        // ---- compute: gates for all 64 nodes, this wave's qg
        f32x4 acc[4][4];
        #pragma unroll
        for (int m = 0; m < 4; m++)
            #pragma unroll
            for (int p = 0; p < 4; p++)
                acc[m][p] = (f32x4){bG4[p], bG4[p], bG4[p], bG4[p]};

        const u32x4* wq = (const u32x4*)g_wfrag + wv * 40 * 64 + lane;
        const ushort* Xc = lds + XOFF + cur;
        const ushort* Hc = lds + HOFF + cur;
        #pragma unroll
        for (int kc = 0; kc < 10; kc++) {
            bf16x8 bfr[4];
            #pragma unroll
            for (int p = 0; p < 4; p++) {
                u32x4 u = wq[(kc * 4 + p) * 64];
                bfr[p] = *(const bf16x8*)&u;
            }
            const ushort* ab = ((kc < 5) ? (Xc + kc * 32) : (Hc + (kc - 5) * 32)) + aoff;
            bf16x8 afr[4];
            #pragma unroll
            for (int m = 0; m < 4; m++)
                afr[m] = *(const bf16x8*)(ab + m * (16 * LS));
            #pragma unroll
            for (int m = 0; m < 4; m++)
                #pragma unroll
                for (int p = 0; p < 4; p++)
                    acc[m][p] = __builtin_amdgcn_mfma_f32_16x16x32_bf16(
                        afr[m], bfr[p], acc[m][p], 0, 0, 0);
        }

        // ---- elementwise + commit h(t) straight to Hb[nxt]
        ushort* Hn = lds + HOFF + nxt;
        #pragma unroll
        for (int m = 0; m < 4; m++) {
            #pragma unroll
            for (int r = 0; r < 4; r++) {
                float c = sigmoid_fast(acc[m][1][r]) * c_st[m][r]
                        + sigmoid_fast(acc[m][0][r]) * tanh_fast(acc[m][2][r]);
                c_st[m][r] = c;
                float h = sigmoid_fast(acc[m][3][r]) * tanh_fast(c);
                Hn[hoff + (m * 16 + r) * LS] = f2bf(h);
            }
        }
    }

    __syncthreads();   // Hb[0]=h(15), Xb[0]=own h_in rows (t=15 wrote nxt=0)

    // out = relu([h_last | h_in] @ [W_l | W_r]^T + b_l)
    // waves 0..7: (m = wv&3, phalf = wv>>2); waves 8,9 idle (no barriers after)
    if (wv < 8) {
        const int m = wv & 3, pb = (wv >> 2) * 4;
        f32x4 acc[4];
        #pragma unroll
        for (int p = 0; p < 4; p++) {
            float b = bl[(pb + p) * 16 + col];
            acc[p] = (f32x4){b, b, b, b};
        }
        const u32x4* wq2 = (const u32x4*)g_wlrfrag + lane;
        #pragma unroll
        for (int kc = 0; kc < 10; kc++) {
            bf16x8 bfr[4];
            #pragma unroll
            for (int p = 0; p < 4; p++) {
                u32x4 u = wq2[(kc * 8 + pb + p) * 64];
                bfr[p] = *(const bf16x8*)&u;
            }
            const ushort* ab = ((kc < 5) ? (lds + HOFF + kc * 32) : (lds + XOFF + (kc - 5) * 32))
                               + (m * 16 + col) * LS + quad * 8;
            bf16x8 afr = *(const bf16x8*)ab;
            #pragma unroll
            for (int p = 0; p < 4; p++)
                acc[p] = __builtin_amdgcn_mfma_f32_16x16x32_bf16(afr, bfr[p], acc[p], 0, 0, 0);
        }
        #pragma unroll
        for (int p = 0; p < 4; p++) {
            int ocol = (pb + p) * 16 + col;
            #pragma unroll
            for (int r = 0; r < 4; r++) {
                int node = nb + m * 16 + quad * 4 + r;
                if (node < N_NODES) {
                    float v = acc[p][r];
                    out[node * OUT_CH + ocol] = v > 0.f ? v : 0.f;
                }
            }
        }
    }
}

// ---------------------------------------------------------------------------
// FALLBACK: R8 kernel (static 43KB LDS, 2 barriers/step) — used only if the
// 84KB dynamic-LDS attribute probe fails.
// ---------------------------------------------------------------------------
__launch_bounds__(640)
__global__ void lstm_sage_sb(const int* __restrict__ edge_src,
                             const float* __restrict__ bl,
                             float* __restrict__ out)
{
    __shared__ ushort Xb[64 * LS];
    __shared__ ushort Hb[64 * LS];

    const int tid  = threadIdx.x;
    const int lane = tid & 63;
    const int wv   = tid >> 6;
    const int col  = lane & 15, quad = lane >> 4;
    const int nb   = blockIdx.x * 64;

    float bG4[4];
    #pragma unroll
    for (int p = 0; p < 4; p++) bG4[p] = g_bsum[p * 160 + wv * 16 + col];

    for (int i = tid; i < 64 * LS; i += 640) Hb[i] = 0;

    float c_st[4][4];
    #pragma unroll
    for (int m = 0; m < 4; m++)
        #pragma unroll
        for (int r = 0; r < 4; r++) c_st[m][r] = 0.f;

    unsigned hn[4][2];

    const int grow  = tid / 10;
    const int gpart = tid - grow * 10;
    const int node_g = nb + grow;
    const int sbase = (node_g < N_NODES ? node_g : 0) * DEG;

    u32x4 P0, P1;
    {
        int s = edge_src[sbase];
        const u32x4* sp = (const u32x4*)(g_hin + s * F_DIM);
        P0 = sp[gpart]; P1 = sp[gpart + 10];
    }
    int snext = edge_src[sbase + 1];

    #pragma unroll 1
    for (int t = 0; t < NSTEP; t++) {
        if (t > 0) {
            #pragma unroll
            for (int m = 0; m < 4; m++)
                #pragma unroll
                for (int k = 0; k < 2; k++) {
                    int a = (m * 16 + quad * 4 + 2 * k) * LS + wv * 16 + col;
                    unsigned pk = hn[m][k];
                    Hb[a]      = (ushort)pk;
                    Hb[a + LS] = (ushort)(pk >> 16);
                }
        }
        {
            u32x4* dp = (u32x4*)(Xb + grow * LS);
            dp[gpart] = P0; dp[gpart + 10] = P1;
        }
        __syncthreads();

        {
            const u32x4* sp = (t < NSTEP - 1)
                ? (const u32x4*)(g_hin + snext * F_DIM)
                : (const u32x4*)(g_hin + (node_g < N_NODES ? node_g : 0) * F_DIM);
            P0 = sp[gpart]; P1 = sp[gpart + 10];
            snext = edge_src[sbase + ((t + 2 < DEG) ? t + 2 : 0)];
        }

        f32x4 acc[4][4];
        #pragma unroll
        for (int m = 0; m < 4; m++)
            #pragma unroll
            for (int p = 0; p < 4; p++)
                acc[m][p] = (f32x4){bG4[p], bG4[p], bG4[p], bG4[p]};

        const u32x4* wq = (const u32x4*)g_wfrag + wv * 40 * 64 + lane;
        #pragma unroll
        for (int kc = 0; kc < 10; kc++) {
            bf16x8 bfr[4];
            #pragma unroll
            for (int p = 0; p < 4; p++) {
                u32x4 u = wq[(kc * 4 + p) * 64];
                bfr[p] = *(const bf16x8*)&u;
            }
            const ushort* ab = ((kc < 5) ? (Xb + kc * 32) : (Hb + (kc - 5) * 32))
                               + col * LS + quad * 8;
            bf16x8 afr[4];
            #pragma unroll
            for (int m = 0; m < 4; m++)
                afr[m] = *(const bf16x8*)(ab + m * (16 * LS));
            #pragma unroll
            for (int m = 0; m < 4; m++)
                #pragma unroll
                for (int p = 0; p < 4; p++)
                    acc[m][p] = __builtin_amdgcn_mfma_f32_16x16x32_bf16(
                        afr[m], bfr[p], acc[m][p], 0, 0, 0);
        }
        #pragma unroll
        for (int m = 0; m < 4; m++) {
            #pragma unroll
            for (int k = 0; k < 2; k++) {
                unsigned pk = 0;
                #pragma unroll
                for (int h2 = 0; h2 < 2; h2++) {
                    int r = 2 * k + h2;
                    float c = sigmoid_fast(acc[m][1][r]) * c_st[m][r]
                            + sigmoid_fast(acc[m][0][r]) * tanh_fast(acc[m][2][r]);
                    c_st[m][r] = c;
                    float h = sigmoid_fast(acc[m][3][r]) * tanh_fast(c);
                    pk |= ((unsigned)f2bf(h)) << (16 * h2);
                }
                hn[m][k] = pk;
            }
        }
        __syncthreads();
    }

    #pragma unroll
    for (int m = 0; m < 4; m++)
        #pragma unroll
        for (int k = 0; k < 2; k++) {
            int a = (m * 16 + quad * 4 + 2 * k) * LS + wv * 16 + col;
            unsigned pk = hn[m][k];
            Hb[a]      = (ushort)pk;
            Hb[a + LS] = (ushort)(pk >> 16);
        }
    {
        u32x4* dp = (u32x4*)(Xb + grow * LS);
        dp[gpart] = P0; dp[gpart + 10] = P1;
    }
    __syncthreads();

    if (wv < 8) {
        const int m = wv & 3, pb = (wv >> 2) * 4;
        f32x4 acc[4];
        #pragma unroll
        for (int p = 0; p < 4; p++) {
            float b = bl[(pb + p) * 16 + col];
            acc[p] = (f32x4){b, b, b, b};
        }
        const u32x4* wq2 = (const u32x4*)g_wlrfrag + lane;
        #pragma unroll
        for (int kc = 0; kc < 10; kc++) {
            bf16x8 bfr[4];
            #pragma unroll
            for (int p = 0; p < 4; p++) {
                u32x4 u = wq2[(kc * 8 + pb + p) * 64];
                bfr[p] = *(const bf16x8*)&u;
            }
            const ushort* ab = ((kc < 5) ? (Hb + kc * 32) : (Xb + (kc - 5) * 32))
                               + (m * 16 + col) * LS + quad * 8;
            bf16x8 afr = *(const bf16x8*)ab;
            #pragma unroll
            for (int p = 0; p < 4; p++)
                acc[p] = __builtin_amdgcn_mfma_f32_16x16x32_bf16(afr, bfr[p], acc[p], 0, 0, 0);
        }
        #pragma unroll
        for (int p = 0; p < 4; p++) {
            int ocol = (pb + p) * 16 + col;
            #pragma unroll
            for (int r = 0; r < 4; r++) {
                int node = nb + m * 16 + quad * 4 + r;
                if (node < N_NODES) {
                    float v = acc[p][r];
                    out[node * OUT_CH + ocol] = v > 0.f ? v : 0.f;
                }
            }
        }
    }
}

extern "C" void kernel_launch(void* const* d_in, const int* in_sizes, int n_in,
                              void* d_out, int out_size, void* d_ws, size_t ws_size,
                              hipStream_t stream)
{
    const float* x      = (const float*)d_in[0];
    const int*   tids   = (const int*)  d_in[1];
    const int*   esrc   = (const int*)  d_in[2];   // edge_index[0] = src (dst sorted, DEG each)
    const float* emb    = (const float*)d_in[3];
    const float* Wih    = (const float*)d_in[4];
    const float* Whh    = (const float*)d_in[5];
    const float* bih    = (const float*)d_in[6];
    const float* bhh    = (const float*)d_in[7];
    const float* Wl     = (const float*)d_in[8];
    const float* blin   = (const float*)d_in[9];
    const float* Wr     = (const float*)d_in[10];
    float* out = (float*)d_out;

    hipLaunchKernelGGL(pack_kernel, dim3(123), dim3(256), 0, stream,
                       Wih, Whh, bih, bhh, Wl, Wr);
    hipLaunchKernelGGL(build_hin, dim3((N_NODES * F_DIM + 255) / 256), dim3(256), 0, stream,
                       x, tids, emb);

    const int dbShmem = 4 * 64 * LS * (int)sizeof(ushort);   // 86016 B
    (void)hipFuncSetAttribute((const void*)lstm_sage_db,
                              hipFuncAttributeMaxDynamicSharedMemorySize, dbShmem);
    hipFuncAttributes fa;
    bool dbOk = (hipFuncGetAttributes(&fa, (const void*)lstm_sage_db) == hipSuccess) &&
                (fa.maxDynamicSharedSizeBytes >= dbShmem);

    if (dbOk) {
        hipLaunchKernelGGL(lstm_sage_db, dim3((N_NODES + 63) / 64), dim3(640),
                           dbShmem, stream, esrc, blin, out);
    } else {
        hipLaunchKernelGGL(lstm_sage_sb, dim3((N_NODES + 63) / 64), dim3(640),
                           0, stream, esrc, blin, out);
    }
}